// Round 20
// baseline (507.646 us; speedup 1.0000x reference)
//
#include <hip/hip_runtime.h>
#include <stdint.h>

#define NB 4
#define NN 8192
#define KNB 30
#define TOT (NB * NN)

// ---------------- threefry2x32 (JAX-exact, key = [0, 42]) ----------------
__device__ __forceinline__ uint32_t rotl32(uint32_t v, int r) {
    return (v << r) | (v >> (32 - r));
}

__device__ __forceinline__ void threefry(uint32_t x0, uint32_t x1,
                                         uint32_t& o0, uint32_t& o1) {
    const uint32_t ks0 = 0u, ks1 = 42u, ks2 = 0u ^ 42u ^ 0x1BD11BDAu;
    x0 += ks0; x1 += ks1;
#define RND(r) { x0 += x1; x1 = rotl32(x1, r); x1 ^= x0; }
    RND(13) RND(15) RND(26) RND(6)
    x0 += ks1; x1 += ks2 + 1u;
    RND(17) RND(29) RND(16) RND(24)
    x0 += ks2; x1 += ks0 + 2u;
    RND(13) RND(15) RND(26) RND(6)
    x0 += ks0; x1 += ks1 + 3u;
    RND(17) RND(29) RND(16) RND(24)
    x0 += ks1; x1 += ks2 + 4u;
    RND(13) RND(15) RND(26) RND(6)
    x0 += ks2; x1 += ks0 + 5u;
#undef RND
    o0 = x0; o1 = x1;
}

// ---- fused: z init (partitionable threefry) + SoA transpose w/ inf-baking ----
__global__ void prep_kernel(const float* __restrict__ X,
                            const int* __restrict__ C,
                            float* __restrict__ z,
                            float* __restrict__ Xs) {
    int t = blockIdx.x * blockDim.x + threadIdx.x;
    if (t >= TOT) return;
    uint32_t o0, o1;
    threefry(0u, (uint32_t)t, o0, o1);
    uint32_t bits = o0 ^ o1;
    z[t] = __uint_as_float((bits >> 9) | 0x3f800000u) - 1.0f;

    const int b = t >> 13, n = t & (NN - 1);
    const bool valid = C[t] > 0;
    const float INF = __uint_as_float(0x7F800000u);
    const float* src = X + (size_t)t * 3;
    float* dst = Xs + (size_t)b * 3 * NN;
    dst[0 * NN + n] = valid ? src[0] : INF;
    dst[1 * NN + n] = valid ? src[1] : INF;
    dst[2 * NN + n] = valid ? src[2] : INF;
}

// ---------------- kNN: quad-row windowed radix-select, 512 threads -----------
// One block serves rows 4k..4k+3 (same batch: NN%4==0). Each thread owns 16
// candidates per row (e0..e3[16] = 64 d-floats, same reg footprint as R19).
// Two packed hists (A|B, C|D in 16-bit halves; per-copy count <= 512).
// Selection semantics verbatim R19: window level + all-wave scan + fast-path V
// + verbatim 4-level fallback + simple-atomic collect + bitonic-64 per wave.
__global__ __launch_bounds__(512) void knn_kernel(const float* __restrict__ Xs,
                                                  const float* __restrict__ X,
                                                  int* __restrict__ edgesT) {
    const int row0 = blockIdx.x * 4;
    const int b = row0 >> 13;
    const int i0 = row0 & (NN - 1);
    const float* Xsb = Xs + (size_t)b * 3 * NN;
    const float* Xq = X + (size_t)b * NN * 3;
    const float xi0 = Xq[(i0 + 0) * 3 + 0], yi0 = Xq[(i0 + 0) * 3 + 1], zi0 = Xq[(i0 + 0) * 3 + 2];
    const float xi1 = Xq[(i0 + 1) * 3 + 0], yi1 = Xq[(i0 + 1) * 3 + 1], zi1 = Xq[(i0 + 1) * 3 + 2];
    const float xi2 = Xq[(i0 + 2) * 3 + 0], yi2 = Xq[(i0 + 2) * 3 + 1], zi2 = Xq[(i0 + 2) * 3 + 2];
    const float xi3 = Xq[(i0 + 3) * 3 + 0], yi3 = Xq[(i0 + 3) * 3 + 1], zi3 = Xq[(i0 + 3) * 3 + 2];
    const int t = threadIdx.x;
    const uint32_t BIGBITS = __float_as_uint(1e9f);

    float e0[16], e1[16], e2[16], e3[16];
#pragma unroll
    for (int g = 0; g < 4; ++g) {
        const int j0 = g * 2048 + t * 4;
        const float4 x4 = *(const float4*)(Xsb + 0 * NN + j0);
        const float4 y4 = *(const float4*)(Xsb + 1 * NN + j0);
        const float4 z4 = *(const float4*)(Xsb + 2 * NN + j0);
#define LAD(DST, XI, YI, ZI, II, q, xx, yy, zz)                                \
        {                                                                      \
            float dx = __fsub_rn((XI), (xx));                                  \
            float dy = __fsub_rn((YI), (yy));                                  \
            float dz = __fsub_rn((ZI), (zz));                                  \
            float dd = __fadd_rn(__fadd_rn(__fmul_rn(dx, dx),                  \
                                           __fmul_rn(dy, dy)),                 \
                                 __fmul_rn(dz, dz));                           \
            DST[g * 4 + (q)] = __fadd_rn(dd, ((j0 + (q)) == (II)) ? 1e9f : 0.0f); \
        }
#define DQ(q, xx, yy, zz)                                                      \
        LAD(e0, xi0, yi0, zi0, i0 + 0, q, xx, yy, zz)                          \
        LAD(e1, xi1, yi1, zi1, i0 + 1, q, xx, yy, zz)                          \
        LAD(e2, xi2, yi2, zi2, i0 + 2, q, xx, yy, zz)                          \
        LAD(e3, xi3, yi3, zi3, i0 + 3, q, xx, yy, zz)
        DQ(0, x4.x, y4.x, z4.x)
        DQ(1, x4.y, y4.y, z4.y)
        DQ(2, x4.z, y4.z, z4.z)
        DQ(3, x4.w, y4.w, z4.w)
#undef DQ
#undef LAD
    }

#define MKKEY(D, s) ((((unsigned long long)__float_as_uint(D[(s)])) << 32) | \
                     (unsigned)((((s) >> 2) * 2048) + t * 4 + ((s) & 3)))

    __shared__ uint32_t histAB[16][257];  // rows 0|1 packed; +1 pad (257%32==1)
    __shared__ uint32_t histCD[16][257];  // rows 2|3 packed
    __shared__ uint32_t colrow[4][256];
    __shared__ float wminS[8][4];
    __shared__ unsigned long long cbuf4[4][64];
    __shared__ uint32_t ccnt4[4];

    const int sh = t & 15;               // distinct copy per lane within group
    const int l = t & 63;                // lane
    const int w = t >> 6;                // wave (0..7)
    if (t < 4) ccnt4[t] = 0u;
    for (int idx = t; idx < 16 * 257; idx += 512) {
        (&histAB[0][0])[idx] = 0u;
        (&histCD[0][0])[idx] = 0u;
    }

    // per-row local min -> wave min -> LDS
    float m0 = e0[0], m1 = e1[0], m2 = e2[0], m3 = e3[0];
#pragma unroll
    for (int s = 1; s < 16; ++s) {
        m0 = fminf(m0, e0[s]); m1 = fminf(m1, e1[s]);
        m2 = fminf(m2, e2[s]); m3 = fminf(m3, e3[s]);
    }
#pragma unroll
    for (int off = 32; off >= 1; off >>= 1) {
        m0 = fminf(m0, __shfl_xor(m0, off, 64));
        m1 = fminf(m1, __shfl_xor(m1, off, 64));
        m2 = fminf(m2, __shfl_xor(m2, off, 64));
        m3 = fminf(m3, __shfl_xor(m3, off, 64));
    }
    if (l == 0) { wminS[w][0] = m0; wminS[w][1] = m1; wminS[w][2] = m2; wminS[w][3] = m3; }
    __syncthreads();                     // publishes wmin, hist zero, ccnt
#define BMIN(R)                                                                \
    (__float_as_uint(fminf(fminf(fminf(wminS[0][R], wminS[1][R]),              \
                                 fminf(wminS[2][R], wminS[3][R])),             \
                           fminf(fminf(wminS[4][R], wminS[5][R]),              \
                                 fminf(wminS[6][R], wminS[7][R])))) >> 20)
    const uint32_t base0 = BMIN(0), base1 = BMIN(1), base2 = BMIN(2), base3 = BMIN(3);
#undef BMIN

    // windowed histogram level, 4 rows packed into 2 arrays
#pragma unroll
    for (int s = 0; s < 16; ++s) {
        uint32_t hb0 = __float_as_uint(e0[s]);
        if (hb0 < BIGBITS) {
            uint32_t bs = (hb0 >> 20) - base0; bs = bs < 255u ? bs : 255u;
            atomicAdd(&histAB[sh][bs], 1u);
        }
        uint32_t hb1 = __float_as_uint(e1[s]);
        if (hb1 < BIGBITS) {
            uint32_t bs = (hb1 >> 20) - base1; bs = bs < 255u ? bs : 255u;
            atomicAdd(&histAB[sh][bs], 0x10000u);
        }
        uint32_t hb2 = __float_as_uint(e2[s]);
        if (hb2 < BIGBITS) {
            uint32_t bs = (hb2 >> 20) - base2; bs = bs < 255u ? bs : 255u;
            atomicAdd(&histCD[sh][bs], 1u);
        }
        uint32_t hb3 = __float_as_uint(e3[s]);
        if (hb3 < BIGBITS) {
            uint32_t bs = (hb3 >> 20) - base3; bs = bs < 255u ? bs : 255u;
            atomicAdd(&histCD[sh][bs], 0x10000u);
        }
    }
    __syncthreads();
    if (t < 256) {
        uint32_t cs0 = 0, cs1 = 0, cs2 = 0, cs3 = 0;
#pragma unroll
        for (int q = 0; q < 16; ++q) {
            uint32_t hA = histAB[q][t];  // lazy: no re-zero on fast path
            cs0 += hA & 0xFFFFu; cs1 += hA >> 16;
            uint32_t hC = histCD[q][t];
            cs2 += hC & 0xFFFFu; cs3 += hC >> 16;
        }
        colrow[0][t] = cs0; colrow[1][t] = cs1;
        colrow[2][t] = cs2; colrow[3][t] = cs3;
    }
    __syncthreads();

    // all-wave redundant scan per row (registers; identical across waves)
#define SCAN(COLROW, BKT, RR, CB)                                              \
    {                                                                          \
        uint32_t c0 = COLROW[4 * l + 0], c1 = COLROW[4 * l + 1];               \
        uint32_t c2 = COLROW[4 * l + 2], c3 = COLROW[4 * l + 3];               \
        uint32_t lsum = c0 + c1 + c2 + c3;                                     \
        uint32_t inc = lsum;                                                   \
        _Pragma("unroll")                                                      \
        for (int off = 1; off < 64; off <<= 1) {                               \
            uint32_t o = __shfl_up(inc, off, 64);                              \
            if (l >= off) inc += o;                                            \
        }                                                                      \
        uint32_t exc = inc - lsum;                                             \
        const uint32_t r0c = (uint32_t)KNB;                                    \
        bool hit = (exc < r0c && r0c <= inc);                                  \
        unsigned long long mb = __ballot(hit);                                 \
        uint32_t bkt = 0u, rnew = 0u, cBn = 0u;                                \
        if (hit) {                                                             \
            uint32_t e = exc;                                                  \
            if (r0c <= e + c0)                { bkt = 4u*l+0u; cBn = c0; }     \
            else if (r0c <= e + c0 + c1)      { bkt = 4u*l+1u; cBn = c1; e += c0; } \
            else if (r0c <= e + c0 + c1 + c2) { bkt = 4u*l+2u; cBn = c2; e += c0 + c1; } \
            else                              { bkt = 4u*l+3u; cBn = c3; e += c0 + c1 + c2; } \
            rnew = r0c - e;                                                    \
        }                                                                      \
        const int srcl = (int)(__ffsll((long long)mb) - 1);                    \
        BKT = __shfl(bkt, srcl, 64);                                           \
        RR = __shfl(rnew, srcl, 64);                                           \
        CB = __shfl(cBn, srcl, 64);                                            \
    }

    uint32_t bk0, rr0, cb0, bk1, rr1, cb1, bk2, rr2, cb2, bk3, rr3, cb3;
    SCAN(colrow[0], bk0, rr0, cb0)
    SCAN(colrow[1], bk1, rr1, cb1)
    SCAN(colrow[2], bk2, rr2, cb2)
    SCAN(colrow[3], bk3, rr3, cb3)

    // slow fallback (rare; block-uniform per row): R15 4-level, full-width,
    // zeroes histAB for itself (lazy-zero scheme), colrow[R] as scratch.
#define FALLBACK(D, CR, VOUT)                                                  \
    {                                                                          \
        for (int idx = t; idx < 16 * 257; idx += 512)                          \
            (&histAB[0][0])[idx] = 0u;                                         \
        __syncthreads();                                                       \
        uint32_t pref = 0u, r = (uint32_t)KNB, cB = 0u;                        \
        int exitShift = 0;                                                     \
        for (int L = 0; L < 4; ++L) {                                          \
            const int shift = 24 - 8 * L;                                      \
            const uint32_t pmask = (L == 0) ? 0u : (0xFFFFFFFFu << (32 - 8 * L)); \
            _Pragma("unroll")                                                  \
            for (int s = 0; s < 16; ++s) {                                     \
                uint32_t hb = __float_as_uint(D[s]);                           \
                if ((hb & pmask) == pref && hb < BIGBITS)                      \
                    atomicAdd(&histAB[sh][(hb >> shift) & 255], 1u);           \
            }                                                                  \
            __syncthreads();                                                   \
            if (t < 256) {                                                     \
                uint32_t cs = 0;                                               \
                _Pragma("unroll")                                              \
                for (int q = 0; q < 16; ++q) { cs += histAB[q][t]; histAB[q][t] = 0u; } \
                CR[t] = cs;                                                    \
            }                                                                  \
            __syncthreads();                                                   \
            uint32_t bkt2, rnew2, cbx;                                         \
            SCAN(CR, bkt2, rnew2, cbx)                                         \
            unsigned long long any = __ballot(rnew2 != 0u || cbx != 0u);       \
            if (any != 0ull) {                                                 \
                pref = pref | (bkt2 << shift);                                 \
                r = rnew2;                                                     \
                cB = cbx;                                                      \
            }                                                                  \
            if ((uint32_t)KNB - r + cB <= 64u) { exitShift = shift; break; }   \
        }                                                                      \
        VOUT = pref | ((exitShift > 0) ? ((1u << exitShift) - 1u) : 0u);       \
    }

    uint32_t V0, V1, V2, V3;
    if (bk0 < 255u && (uint32_t)KNB - rr0 + cb0 <= 64u) {
        V0 = ((base0 + bk0 + 1u) << 20) - 1u;
    } else { __syncthreads(); FALLBACK(e0, colrow[0], V0) }
    if (bk1 < 255u && (uint32_t)KNB - rr1 + cb1 <= 64u) {
        V1 = ((base1 + bk1 + 1u) << 20) - 1u;
    } else { __syncthreads(); FALLBACK(e1, colrow[1], V1) }
    if (bk2 < 255u && (uint32_t)KNB - rr2 + cb2 <= 64u) {
        V2 = ((base2 + bk2 + 1u) << 20) - 1u;
    } else { __syncthreads(); FALLBACK(e2, colrow[2], V2) }
    if (bk3 < 255u && (uint32_t)KNB - rr3 + cb3 <= 64u) {
        V3 = ((base3 + bk3 + 1u) << 20) - 1u;
    } else { __syncthreads(); FALLBACK(e3, colrow[3], V3) }
#undef FALLBACK
#undef SCAN

    // collect (simple per-hit atomic — R15-proven faster than ballot compact)
#pragma unroll
    for (int s = 0; s < 16; ++s) {
#define COL(D, V, R)                                                           \
        {                                                                      \
            uint32_t hb = __float_as_uint(D[s]);                               \
            if (hb <= V) {                                                     \
                uint32_t p = atomicAdd(&ccnt4[R], 1u);                         \
                if (p < 64u) cbuf4[R][p] = MKKEY(D, s);                        \
            }                                                                  \
        }
        COL(e0, V0, 0)
        COL(e1, V1, 1)
        COL(e2, V2, 2)
        COL(e3, V3, 3)
#undef COL
    }
#undef MKKEY
    __syncthreads();
    // waves 0..3 each bitonic-sort one row (proven network)
    if (w < 4) {
        const uint32_t nc = ccnt4[w] < 64u ? ccnt4[w] : 64u;
        unsigned long long key = ((uint32_t)l < nc) ? cbuf4[w][l] : ~0ull;
#pragma unroll
        for (int k = 2; k <= 64; k <<= 1) {
            for (int j2 = k >> 1; j2 > 0; j2 >>= 1) {
                unsigned long long o = __shfl_xor(key, j2, 64);
                bool up = ((l & k) == 0);
                bool lower = ((l & j2) == 0);
                unsigned long long mn2 = key < o ? key : o;
                unsigned long long mx = key < o ? o : key;
                key = (up == lower) ? mn2 : mx;
            }
        }
        if (l < KNB)
            edgesT[(size_t)l * TOT + row0 + w] = (int)(key & 0xffffffffu);
    }
}

// ------- one smoothing step (edgesT[k][row]: coalesced neighbor loads) -------
__global__ void smooth_kernel(const float* __restrict__ zin,
                              float* __restrict__ zout,
                              const int* __restrict__ edgesT,
                              const int* __restrict__ C) {
    int t = blockIdx.x * blockDim.x + threadIdx.x;
    if (t >= TOT) return;
    float acc = 0.0f;
    if (C[t] > 0) {
        const int b = t >> 13;
        const float* zb = zin + (size_t)b * NN;
#pragma unroll
        for (int k = 0; k < KNB; ++k)
            acc = __fadd_rn(acc, zb[edgesT[(size_t)k * TOT + t]]);
        acc = __fdiv_rn(acc, __fadd_rn(30.0f, 1e-5f));
    }
    zout[t] = acc;
}

// ---------------- z += priority; stable ascending argsort per batch ----------
__global__ __launch_bounds__(1024) void sort_kernel(const float* __restrict__ z,
                                                    const float* __restrict__ prio,
                                                    int* __restrict__ out) {
    __shared__ unsigned long long keys[NN];  // 64 KiB
    const int b = blockIdx.x;
    for (int i = threadIdx.x; i < NN; i += 1024) {
        float v = z[(size_t)b * NN + i] + prio[(size_t)b * NN + i];
        uint32_t u = __float_as_uint(v);
        u ^= (u >> 31) ? 0xFFFFFFFFu : 0x80000000u;  // monotonic float->uint
        keys[i] = ((unsigned long long)u << 32) | (unsigned)i;
    }
    __syncthreads();
    for (int k = 2; k <= NN; k <<= 1) {
        for (int j = k >> 1; j > 0; j >>= 1) {
            for (int i = threadIdx.x; i < NN; i += 1024) {
                int ixj = i ^ j;
                if (ixj > i) {
                    unsigned long long a = keys[i], c = keys[ixj];
                    bool up = ((i & k) == 0);
                    if ((a > c) == up) { keys[i] = c; keys[ixj] = a; }
                }
            }
            __syncthreads();
        }
    }
    for (int i = threadIdx.x; i < NN; i += 1024)
        out[(size_t)b * NN + i] = (int)(keys[i] & 0xffffffffu);
}

extern "C" void kernel_launch(void* const* d_in, const int* in_sizes, int n_in,
                              void* d_out, int out_size, void* d_ws, size_t ws_size,
                              hipStream_t stream) {
    const float* X = (const float*)d_in[0];    // [4,8192,3] f32
    const int* C = (const int*)d_in[1];        // [4,8192] int32
    const float* prio = (const float*)d_in[2]; // [4,8192] f32
    int* out = (int*)d_out;                    // [4,8192] i32

    float* z0 = (float*)d_ws;
    float* z1 = z0 + TOT;
    int* edgesT = (int*)(z1 + TOT);            // [KNB][TOT]
    float* Xs = (float*)(edgesT + (size_t)TOT * KNB);  // [NB][3][NN]

    prep_kernel<<<TOT / 256, 256, 0, stream>>>(X, C, z0, Xs);
    knn_kernel<<<TOT / 4, 512, 0, stream>>>(Xs, X, edgesT);

    float* cur = z0;
    float* nxt = z1;
    for (int s = 0; s < 5; ++s) {
        smooth_kernel<<<TOT / 256, 256, 0, stream>>>(cur, nxt, edgesT, C);
        float* tmp = cur; cur = nxt; nxt = tmp;
    }
    sort_kernel<<<NB, 1024, 0, stream>>>(cur, prio, out);
}

// Round 21
// 328.460 us; speedup vs baseline: 1.5455x; 1.5455x over previous
//
#include <hip/hip_runtime.h>
#include <stdint.h>

#define NB 4
#define NN 8192
#define KNB 30
#define TOT (NB * NN)

// ---------------- threefry2x32 (JAX-exact, key = [0, 42]) ----------------
__device__ __forceinline__ uint32_t rotl32(uint32_t v, int r) {
    return (v << r) | (v >> (32 - r));
}

__device__ __forceinline__ void threefry(uint32_t x0, uint32_t x1,
                                         uint32_t& o0, uint32_t& o1) {
    const uint32_t ks0 = 0u, ks1 = 42u, ks2 = 0u ^ 42u ^ 0x1BD11BDAu;
    x0 += ks0; x1 += ks1;
#define RND(r) { x0 += x1; x1 = rotl32(x1, r); x1 ^= x0; }
    RND(13) RND(15) RND(26) RND(6)
    x0 += ks1; x1 += ks2 + 1u;
    RND(17) RND(29) RND(16) RND(24)
    x0 += ks2; x1 += ks0 + 2u;
    RND(13) RND(15) RND(26) RND(6)
    x0 += ks0; x1 += ks1 + 3u;
    RND(17) RND(29) RND(16) RND(24)
    x0 += ks1; x1 += ks2 + 4u;
    RND(13) RND(15) RND(26) RND(6)
    x0 += ks2; x1 += ks0 + 5u;
#undef RND
    o0 = x0; o1 = x1;
}

// ---- fused: z init (partitionable threefry) + SoA transpose w/ inf-baking ----
__global__ void prep_kernel(const float* __restrict__ X,
                            const int* __restrict__ C,
                            float* __restrict__ z,
                            float* __restrict__ Xs) {
    int t = blockIdx.x * blockDim.x + threadIdx.x;
    if (t >= TOT) return;
    uint32_t o0, o1;
    threefry(0u, (uint32_t)t, o0, o1);
    uint32_t bits = o0 ^ o1;
    z[t] = __uint_as_float((bits >> 9) | 0x3f800000u) - 1.0f;

    const int b = t >> 13, n = t & (NN - 1);
    const bool valid = C[t] > 0;
    const float INF = __uint_as_float(0x7F800000u);
    const float* src = X + (size_t)t * 3;
    float* dst = Xs + (size_t)b * 3 * NN;
    dst[0 * NN + n] = valid ? src[0] : INF;
    dst[1 * NN + n] = valid ? src[1] : INF;
    dst[2 * NN + n] = valid ? src[2] : INF;
}

// ---------------- kNN: dual-row windowed radix-select, packed histogram ------
// One block serves rows 2k, 2k+1. PACKED hist: row A counts in low 16 bits,
// row B in high 16 (per-copy bucket count <= 512 -> no carry). 16 copies kept
// (4-way same-address degree). LDS ~19.6KB. Lazy zero: fast path never
// re-zeroes; fallback zeroes for itself. (R19-proven optimum.)
__global__ __launch_bounds__(256) void knn_kernel(const float* __restrict__ Xs,
                                                  const float* __restrict__ X,
                                                  int* __restrict__ edgesT) {
    const int rowA = blockIdx.x * 2;
    const int rowB = rowA + 1;
    const int b = rowA >> 13;
    const int iA = rowA & (NN - 1);
    const int iB = iA + 1;
    const float* Xsb = Xs + (size_t)b * 3 * NN;
    const float* Xq = X + (size_t)b * NN * 3;
    const float xiA = Xq[iA * 3 + 0], yiA = Xq[iA * 3 + 1], ziA = Xq[iA * 3 + 2];
    const float xiB = Xq[iB * 3 + 0], yiB = Xq[iB * 3 + 1], ziB = Xq[iB * 3 + 2];
    const int t = threadIdx.x;
    const uint32_t BIGBITS = __float_as_uint(1e9f);

    float dA[32], dB[32];
#pragma unroll
    for (int g = 0; g < 8; ++g) {
        const int j0 = g * 1024 + t * 4;
        const float4 x4 = *(const float4*)(Xsb + 0 * NN + j0);
        const float4 y4 = *(const float4*)(Xsb + 1 * NN + j0);
        const float4 z4 = *(const float4*)(Xsb + 2 * NN + j0);
#define D2(q, xx, yy, zz)                                                      \
        {                                                                      \
            float dx = __fsub_rn(xiA, (xx));                                   \
            float dy = __fsub_rn(yiA, (yy));                                   \
            float dz = __fsub_rn(ziA, (zz));                                   \
            float d2 = __fadd_rn(__fadd_rn(__fmul_rn(dx, dx),                  \
                                           __fmul_rn(dy, dy)),                 \
                                 __fmul_rn(dz, dz));                           \
            dA[g * 4 + (q)] = __fadd_rn(d2, ((j0 + (q)) == iA) ? 1e9f : 0.0f); \
            float ex = __fsub_rn(xiB, (xx));                                   \
            float ey = __fsub_rn(yiB, (yy));                                   \
            float ez = __fsub_rn(ziB, (zz));                                   \
            float e2 = __fadd_rn(__fadd_rn(__fmul_rn(ex, ex),                  \
                                           __fmul_rn(ey, ey)),                 \
                                 __fmul_rn(ez, ez));                           \
            dB[g * 4 + (q)] = __fadd_rn(e2, ((j0 + (q)) == iB) ? 1e9f : 0.0f); \
        }
        D2(0, x4.x, y4.x, z4.x)
        D2(1, x4.y, y4.y, z4.y)
        D2(2, x4.z, y4.z, z4.z)
        D2(3, x4.w, y4.w, z4.w)
#undef D2
    }

#define MKKEY(D, s) ((((unsigned long long)__float_as_uint(D[(s)])) << 32) | \
                     (unsigned)((((s) >> 2) * 1024) + t * 4 + ((s) & 3)))

    __shared__ uint32_t hist[16][257];   // packed A|B; +1 pad: 257 % 32 == 1
    __shared__ uint32_t colrowA[256], colrowB[256];
    __shared__ float wminA[4], wminB[4];
    __shared__ unsigned long long cbufA[64], cbufB[64];
    __shared__ uint32_t ccntA, ccntB;

    const int sh = t & 15;               // distinct copy per lane within group
    const int l = t & 63;                // lane
    const int w = t >> 6;                // wave
    if (t == 0) { ccntA = 0u; ccntB = 0u; }
#pragma unroll
    for (int q = 0; q < 16; ++q) hist[q][t] = 0u;

    // block-min of d2 per row (floats >= 0, no NaN -> float min == bits min)
    float mnA = dA[0], mnB = dB[0];
#pragma unroll
    for (int s = 1; s < 32; ++s) { mnA = fminf(mnA, dA[s]); mnB = fminf(mnB, dB[s]); }
#pragma unroll
    for (int off = 32; off >= 1; off >>= 1) {
        mnA = fminf(mnA, __shfl_xor(mnA, off, 64));
        mnB = fminf(mnB, __shfl_xor(mnB, off, 64));
    }
    if (l == 0) { wminA[w] = mnA; wminB[w] = mnB; }
    __syncthreads();                     // publishes wmin, hist zero, ccnt
    const uint32_t baseA = __float_as_uint(
        fminf(fminf(wminA[0], wminA[1]), fminf(wminA[2], wminA[3]))) >> 20;
    const uint32_t baseB = __float_as_uint(
        fminf(fminf(wminB[0], wminB[1]), fminf(wminB[2], wminB[3]))) >> 20;

    // windowed histogram level, both rows packed into one array
#pragma unroll
    for (int s = 0; s < 32; ++s) {
        uint32_t hbA = __float_as_uint(dA[s]);
        if (hbA < BIGBITS) {
            uint32_t bs = (hbA >> 20) - baseA;
            bs = bs < 255u ? bs : 255u;
            atomicAdd(&hist[sh][bs], 1u);
        }
        uint32_t hbB = __float_as_uint(dB[s]);
        if (hbB < BIGBITS) {
            uint32_t bs = (hbB >> 20) - baseB;
            bs = bs < 255u ? bs : 255u;
            atomicAdd(&hist[sh][bs], 0x10000u);
        }
    }
    __syncthreads();
    {
        uint32_t csA = 0, csB = 0;
#pragma unroll
        for (int q = 0; q < 16; ++q) {
            uint32_t h = hist[q][t];     // lazy: no re-zero on fast path
            csA += h & 0xFFFFu;
            csB += h >> 16;
        }
        colrowA[t] = csA;
        colrowB[t] = csB;
    }
    __syncthreads();

    // all-wave redundant scan per row (registers; identical across waves)
#define SCAN(COLROW, BKT, RR, CB)                                              \
    {                                                                          \
        uint32_t c0 = COLROW[4 * l + 0], c1 = COLROW[4 * l + 1];               \
        uint32_t c2 = COLROW[4 * l + 2], c3 = COLROW[4 * l + 3];               \
        uint32_t lsum = c0 + c1 + c2 + c3;                                     \
        uint32_t inc = lsum;                                                   \
        _Pragma("unroll")                                                      \
        for (int off = 1; off < 64; off <<= 1) {                               \
            uint32_t o = __shfl_up(inc, off, 64);                              \
            if (l >= off) inc += o;                                            \
        }                                                                      \
        uint32_t exc = inc - lsum;                                             \
        const uint32_t r0 = (uint32_t)KNB;                                     \
        bool hit = (exc < r0 && r0 <= inc);                                    \
        unsigned long long mb = __ballot(hit);                                 \
        uint32_t bkt = 0u, rnew = 0u, cBn = 0u;                                \
        if (hit) {                                                             \
            uint32_t e = exc;                                                  \
            if (r0 <= e + c0)                { bkt = 4u*l+0u; cBn = c0; }      \
            else if (r0 <= e + c0 + c1)      { bkt = 4u*l+1u; cBn = c1; e += c0; } \
            else if (r0 <= e + c0 + c1 + c2) { bkt = 4u*l+2u; cBn = c2; e += c0 + c1; } \
            else                             { bkt = 4u*l+3u; cBn = c3; e += c0 + c1 + c2; } \
            rnew = r0 - e;                                                     \
        }                                                                      \
        const int srcl = (int)(__ffsll((long long)mb) - 1);                    \
        BKT = __shfl(bkt, srcl, 64);                                           \
        RR = __shfl(rnew, srcl, 64);                                           \
        CB = __shfl(cBn, srcl, 64);                                            \
    }

    uint32_t bktA, rA, cBA, bktB, rB, cBB;
    SCAN(colrowA, bktA, rA, cBA)
    SCAN(colrowB, bktB, rB, cBB)

    // slow fallback (rare; block-uniform per row): R15 4-level, full-width
    // counts, zeroes hist for itself (lazy-zero scheme).
#define FALLBACK(D, COLROW, VOUT)                                              \
    {                                                                          \
        _Pragma("unroll")                                                      \
        for (int q = 0; q < 16; ++q) hist[q][t] = 0u;                          \
        __syncthreads();                                                       \
        uint32_t pref = 0u, r = (uint32_t)KNB, cB = 0u;                        \
        int exitShift = 0;                                                     \
        for (int L = 0; L < 4; ++L) {                                          \
            const int shift = 24 - 8 * L;                                      \
            const uint32_t pmask = (L == 0) ? 0u : (0xFFFFFFFFu << (32 - 8 * L)); \
            _Pragma("unroll")                                                  \
            for (int s = 0; s < 32; ++s) {                                     \
                uint32_t hb = __float_as_uint(D[s]);                           \
                if ((hb & pmask) == pref && hb < BIGBITS)                      \
                    atomicAdd(&hist[sh][(hb >> shift) & 255], 1u);             \
            }                                                                  \
            __syncthreads();                                                   \
            uint32_t cs = 0;                                                   \
            _Pragma("unroll")                                                  \
            for (int q = 0; q < 16; ++q) { cs += hist[q][t]; hist[q][t] = 0u; } \
            COLROW[t] = cs;                                                    \
            __syncthreads();                                                   \
            uint32_t bkt2, rnew2, cb2;                                         \
            SCAN(COLROW, bkt2, rnew2, cb2)                                     \
            unsigned long long any = __ballot(rnew2 != 0u || cb2 != 0u);       \
            if (any != 0ull) {                                                 \
                pref = pref | (bkt2 << shift);                                 \
                r = rnew2;                                                     \
                cB = cb2;                                                      \
            }                                                                  \
            if ((uint32_t)KNB - r + cB <= 64u) { exitShift = shift; break; }   \
        }                                                                      \
        VOUT = pref | ((exitShift > 0) ? ((1u << exitShift) - 1u) : 0u);       \
    }

    uint32_t V_A, V_B;
    if (bktA < 255u && (uint32_t)KNB - rA + cBA <= 64u) {
        V_A = ((baseA + bktA + 1u) << 20) - 1u;
    } else {
        __syncthreads();
        FALLBACK(dA, colrowA, V_A)
    }
    if (bktB < 255u && (uint32_t)KNB - rB + cBB <= 64u) {
        V_B = ((baseB + bktB + 1u) << 20) - 1u;
    } else {
        __syncthreads();
        FALLBACK(dB, colrowB, V_B)
    }
#undef FALLBACK
#undef SCAN

    // collect (simple per-hit atomic — R15-proven faster than ballot compact)
#pragma unroll
    for (int s = 0; s < 32; ++s) {
        uint32_t hbA = __float_as_uint(dA[s]);
        if (hbA <= V_A) {
            uint32_t p = atomicAdd(&ccntA, 1u);
            if (p < 64u) cbufA[p] = MKKEY(dA, s);
        }
        uint32_t hbB = __float_as_uint(dB[s]);
        if (hbB <= V_B) {
            uint32_t p = atomicAdd(&ccntB, 1u);
            if (p < 64u) cbufB[p] = MKKEY(dB, s);
        }
    }
#undef MKKEY
    __syncthreads();
    // wave 0 sorts row A, wave 1 sorts row B (proven bitonic-64 network)
    if (w < 2) {
        const uint32_t n = (w == 0) ? (ccntA < 64u ? ccntA : 64u)
                                    : (ccntB < 64u ? ccntB : 64u);
        unsigned long long key =
            ((uint32_t)l < n) ? (w == 0 ? cbufA[l] : cbufB[l]) : ~0ull;
#pragma unroll
        for (int k = 2; k <= 64; k <<= 1) {
            for (int j2 = k >> 1; j2 > 0; j2 >>= 1) {
                unsigned long long o = __shfl_xor(key, j2, 64);
                bool up = ((l & k) == 0);
                bool lower = ((l & j2) == 0);
                unsigned long long mn2 = key < o ? key : o;
                unsigned long long mx = key < o ? o : key;
                key = (up == lower) ? mn2 : mx;
            }
        }
        if (l < KNB)
            edgesT[(size_t)l * TOT + (w == 0 ? rowA : rowB)] =
                (int)(key & 0xffffffffu);
    }
}

// ------- one smoothing step (edgesT[k][row]: coalesced neighbor loads) -------
__global__ void smooth_kernel(const float* __restrict__ zin,
                              float* __restrict__ zout,
                              const int* __restrict__ edgesT,
                              const int* __restrict__ C) {
    int t = blockIdx.x * blockDim.x + threadIdx.x;
    if (t >= TOT) return;
    float acc = 0.0f;
    if (C[t] > 0) {
        const int b = t >> 13;
        const float* zb = zin + (size_t)b * NN;
#pragma unroll
        for (int k = 0; k < KNB; ++k)
            acc = __fadd_rn(acc, zb[edgesT[(size_t)k * TOT + t]]);
        acc = __fdiv_rn(acc, __fadd_rn(30.0f, 1e-5f));
    }
    zout[t] = acc;
}

// ---------------- z += priority; stable ascending argsort per batch ----------
__global__ __launch_bounds__(1024) void sort_kernel(const float* __restrict__ z,
                                                    const float* __restrict__ prio,
                                                    int* __restrict__ out) {
    __shared__ unsigned long long keys[NN];  // 64 KiB
    const int b = blockIdx.x;
    for (int i = threadIdx.x; i < NN; i += 1024) {
        float v = z[(size_t)b * NN + i] + prio[(size_t)b * NN + i];
        uint32_t u = __float_as_uint(v);
        u ^= (u >> 31) ? 0xFFFFFFFFu : 0x80000000u;  // monotonic float->uint
        keys[i] = ((unsigned long long)u << 32) | (unsigned)i;
    }
    __syncthreads();
    for (int k = 2; k <= NN; k <<= 1) {
        for (int j = k >> 1; j > 0; j >>= 1) {
            for (int i = threadIdx.x; i < NN; i += 1024) {
                int ixj = i ^ j;
                if (ixj > i) {
                    unsigned long long a = keys[i], c = keys[ixj];
                    bool up = ((i & k) == 0);
                    if ((a > c) == up) { keys[i] = c; keys[ixj] = a; }
                }
            }
            __syncthreads();
        }
    }
    for (int i = threadIdx.x; i < NN; i += 1024)
        out[(size_t)b * NN + i] = (int)(keys[i] & 0xffffffffu);
}

extern "C" void kernel_launch(void* const* d_in, const int* in_sizes, int n_in,
                              void* d_out, int out_size, void* d_ws, size_t ws_size,
                              hipStream_t stream) {
    const float* X = (const float*)d_in[0];    // [4,8192,3] f32
    const int* C = (const int*)d_in[1];        // [4,8192] int32
    const float* prio = (const float*)d_in[2]; // [4,8192] f32
    int* out = (int*)d_out;                    // [4,8192] i32

    float* z0 = (float*)d_ws;
    float* z1 = z0 + TOT;
    int* edgesT = (int*)(z1 + TOT);            // [KNB][TOT]
    float* Xs = (float*)(edgesT + (size_t)TOT * KNB);  // [NB][3][NN]

    prep_kernel<<<TOT / 256, 256, 0, stream>>>(X, C, z0, Xs);
    knn_kernel<<<TOT / 2, 256, 0, stream>>>(Xs, X, edgesT);

    float* cur = z0;
    float* nxt = z1;
    for (int s = 0; s < 5; ++s) {
        smooth_kernel<<<TOT / 256, 256, 0, stream>>>(cur, nxt, edgesT, C);
        float* tmp = cur; cur = nxt; nxt = tmp;
    }
    sort_kernel<<<NB, 1024, 0, stream>>>(cur, prio, out);
}

// Round 22
// 261.979 us; speedup vs baseline: 1.9377x; 1.2538x over previous
//
#include <hip/hip_runtime.h>
#include <stdint.h>

#define NB 4
#define NN 8192
#define KNB 30
#define TOT (NB * NN)

// ---------------- threefry2x32 (JAX-exact, key = [0, 42]) ----------------
__device__ __forceinline__ uint32_t rotl32(uint32_t v, int r) {
    return (v << r) | (v >> (32 - r));
}

__device__ __forceinline__ void threefry(uint32_t x0, uint32_t x1,
                                         uint32_t& o0, uint32_t& o1) {
    const uint32_t ks0 = 0u, ks1 = 42u, ks2 = 0u ^ 42u ^ 0x1BD11BDAu;
    x0 += ks0; x1 += ks1;
#define RND(r) { x0 += x1; x1 = rotl32(x1, r); x1 ^= x0; }
    RND(13) RND(15) RND(26) RND(6)
    x0 += ks1; x1 += ks2 + 1u;
    RND(17) RND(29) RND(16) RND(24)
    x0 += ks2; x1 += ks0 + 2u;
    RND(13) RND(15) RND(26) RND(6)
    x0 += ks0; x1 += ks1 + 3u;
    RND(17) RND(29) RND(16) RND(24)
    x0 += ks1; x1 += ks2 + 4u;
    RND(13) RND(15) RND(26) RND(6)
    x0 += ks2; x1 += ks0 + 5u;
#undef RND
    o0 = x0; o1 = x1;
}

// ---- fused: z init (partitionable threefry) + SoA transpose w/ inf-baking ----
__global__ void prep_kernel(const float* __restrict__ X,
                            const int* __restrict__ C,
                            float* __restrict__ z,
                            float* __restrict__ Xs) {
    int t = blockIdx.x * blockDim.x + threadIdx.x;
    if (t >= TOT) return;
    uint32_t o0, o1;
    threefry(0u, (uint32_t)t, o0, o1);
    uint32_t bits = o0 ^ o1;
    z[t] = __uint_as_float((bits >> 9) | 0x3f800000u) - 1.0f;

    const int b = t >> 13, n = t & (NN - 1);
    const bool valid = C[t] > 0;
    const float INF = __uint_as_float(0x7F800000u);
    const float* src = X + (size_t)t * 3;
    float* dst = Xs + (size_t)b * 3 * NN;
    dst[0 * NN + n] = valid ? src[0] : INF;
    dst[1 * NN + n] = valid ? src[1] : INF;
    dst[2 * NN + n] = valid ? src[2] : INF;
}

// ---------------- kNN: dual-row windowed radix-select, packed histogram ------
// (R19/R21-proven optimum — verbatim.)
__global__ __launch_bounds__(256) void knn_kernel(const float* __restrict__ Xs,
                                                  const float* __restrict__ X,
                                                  int* __restrict__ edgesT) {
    const int rowA = blockIdx.x * 2;
    const int rowB = rowA + 1;
    const int b = rowA >> 13;
    const int iA = rowA & (NN - 1);
    const int iB = iA + 1;
    const float* Xsb = Xs + (size_t)b * 3 * NN;
    const float* Xq = X + (size_t)b * NN * 3;
    const float xiA = Xq[iA * 3 + 0], yiA = Xq[iA * 3 + 1], ziA = Xq[iA * 3 + 2];
    const float xiB = Xq[iB * 3 + 0], yiB = Xq[iB * 3 + 1], ziB = Xq[iB * 3 + 2];
    const int t = threadIdx.x;
    const uint32_t BIGBITS = __float_as_uint(1e9f);

    float dA[32], dB[32];
#pragma unroll
    for (int g = 0; g < 8; ++g) {
        const int j0 = g * 1024 + t * 4;
        const float4 x4 = *(const float4*)(Xsb + 0 * NN + j0);
        const float4 y4 = *(const float4*)(Xsb + 1 * NN + j0);
        const float4 z4 = *(const float4*)(Xsb + 2 * NN + j0);
#define D2(q, xx, yy, zz)                                                      \
        {                                                                      \
            float dx = __fsub_rn(xiA, (xx));                                   \
            float dy = __fsub_rn(yiA, (yy));                                   \
            float dz = __fsub_rn(ziA, (zz));                                   \
            float d2 = __fadd_rn(__fadd_rn(__fmul_rn(dx, dx),                  \
                                           __fmul_rn(dy, dy)),                 \
                                 __fmul_rn(dz, dz));                           \
            dA[g * 4 + (q)] = __fadd_rn(d2, ((j0 + (q)) == iA) ? 1e9f : 0.0f); \
            float ex = __fsub_rn(xiB, (xx));                                   \
            float ey = __fsub_rn(yiB, (yy));                                   \
            float ez = __fsub_rn(ziB, (zz));                                   \
            float e2 = __fadd_rn(__fadd_rn(__fmul_rn(ex, ex),                  \
                                           __fmul_rn(ey, ey)),                 \
                                 __fmul_rn(ez, ez));                           \
            dB[g * 4 + (q)] = __fadd_rn(e2, ((j0 + (q)) == iB) ? 1e9f : 0.0f); \
        }
        D2(0, x4.x, y4.x, z4.x)
        D2(1, x4.y, y4.y, z4.y)
        D2(2, x4.z, y4.z, z4.z)
        D2(3, x4.w, y4.w, z4.w)
#undef D2
    }

#define MKKEY(D, s) ((((unsigned long long)__float_as_uint(D[(s)])) << 32) | \
                     (unsigned)((((s) >> 2) * 1024) + t * 4 + ((s) & 3)))

    __shared__ uint32_t hist[16][257];   // packed A|B; +1 pad: 257 % 32 == 1
    __shared__ uint32_t colrowA[256], colrowB[256];
    __shared__ float wminA[4], wminB[4];
    __shared__ unsigned long long cbufA[64], cbufB[64];
    __shared__ uint32_t ccntA, ccntB;

    const int sh = t & 15;               // distinct copy per lane within group
    const int l = t & 63;                // lane
    const int w = t >> 6;                // wave
    if (t == 0) { ccntA = 0u; ccntB = 0u; }
#pragma unroll
    for (int q = 0; q < 16; ++q) hist[q][t] = 0u;

    // block-min of d2 per row (floats >= 0, no NaN -> float min == bits min)
    float mnA = dA[0], mnB = dB[0];
#pragma unroll
    for (int s = 1; s < 32; ++s) { mnA = fminf(mnA, dA[s]); mnB = fminf(mnB, dB[s]); }
#pragma unroll
    for (int off = 32; off >= 1; off >>= 1) {
        mnA = fminf(mnA, __shfl_xor(mnA, off, 64));
        mnB = fminf(mnB, __shfl_xor(mnB, off, 64));
    }
    if (l == 0) { wminA[w] = mnA; wminB[w] = mnB; }
    __syncthreads();                     // publishes wmin, hist zero, ccnt
    const uint32_t baseA = __float_as_uint(
        fminf(fminf(wminA[0], wminA[1]), fminf(wminA[2], wminA[3]))) >> 20;
    const uint32_t baseB = __float_as_uint(
        fminf(fminf(wminB[0], wminB[1]), fminf(wminB[2], wminB[3]))) >> 20;

    // windowed histogram level, both rows packed into one array
#pragma unroll
    for (int s = 0; s < 32; ++s) {
        uint32_t hbA = __float_as_uint(dA[s]);
        if (hbA < BIGBITS) {
            uint32_t bs = (hbA >> 20) - baseA;
            bs = bs < 255u ? bs : 255u;
            atomicAdd(&hist[sh][bs], 1u);
        }
        uint32_t hbB = __float_as_uint(dB[s]);
        if (hbB < BIGBITS) {
            uint32_t bs = (hbB >> 20) - baseB;
            bs = bs < 255u ? bs : 255u;
            atomicAdd(&hist[sh][bs], 0x10000u);
        }
    }
    __syncthreads();
    {
        uint32_t csA = 0, csB = 0;
#pragma unroll
        for (int q = 0; q < 16; ++q) {
            uint32_t h = hist[q][t];     // lazy: no re-zero on fast path
            csA += h & 0xFFFFu;
            csB += h >> 16;
        }
        colrowA[t] = csA;
        colrowB[t] = csB;
    }
    __syncthreads();

    // all-wave redundant scan per row (registers; identical across waves)
#define SCAN(COLROW, BKT, RR, CB)                                              \
    {                                                                          \
        uint32_t c0 = COLROW[4 * l + 0], c1 = COLROW[4 * l + 1];               \
        uint32_t c2 = COLROW[4 * l + 2], c3 = COLROW[4 * l + 3];               \
        uint32_t lsum = c0 + c1 + c2 + c3;                                     \
        uint32_t inc = lsum;                                                   \
        _Pragma("unroll")                                                      \
        for (int off = 1; off < 64; off <<= 1) {                               \
            uint32_t o = __shfl_up(inc, off, 64);                              \
            if (l >= off) inc += o;                                            \
        }                                                                      \
        uint32_t exc = inc - lsum;                                             \
        const uint32_t r0 = (uint32_t)KNB;                                     \
        bool hit = (exc < r0 && r0 <= inc);                                    \
        unsigned long long mb = __ballot(hit);                                 \
        uint32_t bkt = 0u, rnew = 0u, cBn = 0u;                                \
        if (hit) {                                                             \
            uint32_t e = exc;                                                  \
            if (r0 <= e + c0)                { bkt = 4u*l+0u; cBn = c0; }      \
            else if (r0 <= e + c0 + c1)      { bkt = 4u*l+1u; cBn = c1; e += c0; } \
            else if (r0 <= e + c0 + c1 + c2) { bkt = 4u*l+2u; cBn = c2; e += c0 + c1; } \
            else                             { bkt = 4u*l+3u; cBn = c3; e += c0 + c1 + c2; } \
            rnew = r0 - e;                                                     \
        }                                                                      \
        const int srcl = (int)(__ffsll((long long)mb) - 1);                    \
        BKT = __shfl(bkt, srcl, 64);                                           \
        RR = __shfl(rnew, srcl, 64);                                           \
        CB = __shfl(cBn, srcl, 64);                                            \
    }

    uint32_t bktA, rA, cBA, bktB, rB, cBB;
    SCAN(colrowA, bktA, rA, cBA)
    SCAN(colrowB, bktB, rB, cBB)

    // slow fallback (rare; block-uniform per row): R15 4-level, full-width
    // counts, zeroes hist for itself (lazy-zero scheme).
#define FALLBACK(D, COLROW, VOUT)                                              \
    {                                                                          \
        _Pragma("unroll")                                                      \
        for (int q = 0; q < 16; ++q) hist[q][t] = 0u;                          \
        __syncthreads();                                                       \
        uint32_t pref = 0u, r = (uint32_t)KNB, cB = 0u;                        \
        int exitShift = 0;                                                     \
        for (int L = 0; L < 4; ++L) {                                          \
            const int shift = 24 - 8 * L;                                      \
            const uint32_t pmask = (L == 0) ? 0u : (0xFFFFFFFFu << (32 - 8 * L)); \
            _Pragma("unroll")                                                  \
            for (int s = 0; s < 32; ++s) {                                     \
                uint32_t hb = __float_as_uint(D[s]);                           \
                if ((hb & pmask) == pref && hb < BIGBITS)                      \
                    atomicAdd(&hist[sh][(hb >> shift) & 255], 1u);             \
            }                                                                  \
            __syncthreads();                                                   \
            uint32_t cs = 0;                                                   \
            _Pragma("unroll")                                                  \
            for (int q = 0; q < 16; ++q) { cs += hist[q][t]; hist[q][t] = 0u; } \
            COLROW[t] = cs;                                                    \
            __syncthreads();                                                   \
            uint32_t bkt2, rnew2, cb2;                                         \
            SCAN(COLROW, bkt2, rnew2, cb2)                                     \
            unsigned long long any = __ballot(rnew2 != 0u || cb2 != 0u);       \
            if (any != 0ull) {                                                 \
                pref = pref | (bkt2 << shift);                                 \
                r = rnew2;                                                     \
                cB = cb2;                                                      \
            }                                                                  \
            if ((uint32_t)KNB - r + cB <= 64u) { exitShift = shift; break; }   \
        }                                                                      \
        VOUT = pref | ((exitShift > 0) ? ((1u << exitShift) - 1u) : 0u);       \
    }

    uint32_t V_A, V_B;
    if (bktA < 255u && (uint32_t)KNB - rA + cBA <= 64u) {
        V_A = ((baseA + bktA + 1u) << 20) - 1u;
    } else {
        __syncthreads();
        FALLBACK(dA, colrowA, V_A)
    }
    if (bktB < 255u && (uint32_t)KNB - rB + cBB <= 64u) {
        V_B = ((baseB + bktB + 1u) << 20) - 1u;
    } else {
        __syncthreads();
        FALLBACK(dB, colrowB, V_B)
    }
#undef FALLBACK
#undef SCAN

    // collect (simple per-hit atomic — R15-proven faster than ballot compact)
#pragma unroll
    for (int s = 0; s < 32; ++s) {
        uint32_t hbA = __float_as_uint(dA[s]);
        if (hbA <= V_A) {
            uint32_t p = atomicAdd(&ccntA, 1u);
            if (p < 64u) cbufA[p] = MKKEY(dA, s);
        }
        uint32_t hbB = __float_as_uint(dB[s]);
        if (hbB <= V_B) {
            uint32_t p = atomicAdd(&ccntB, 1u);
            if (p < 64u) cbufB[p] = MKKEY(dB, s);
        }
    }
#undef MKKEY
    __syncthreads();
    // wave 0 sorts row A, wave 1 sorts row B (proven bitonic-64 network)
    if (w < 2) {
        const uint32_t n = (w == 0) ? (ccntA < 64u ? ccntA : 64u)
                                    : (ccntB < 64u ? ccntB : 64u);
        unsigned long long key =
            ((uint32_t)l < n) ? (w == 0 ? cbufA[l] : cbufB[l]) : ~0ull;
#pragma unroll
        for (int k = 2; k <= 64; k <<= 1) {
            for (int j2 = k >> 1; j2 > 0; j2 >>= 1) {
                unsigned long long o = __shfl_xor(key, j2, 64);
                bool up = ((l & k) == 0);
                bool lower = ((l & j2) == 0);
                unsigned long long mn2 = key < o ? key : o;
                unsigned long long mx = key < o ? o : key;
                key = (up == lower) ? mn2 : mx;
            }
        }
        if (l < KNB)
            edgesT[(size_t)l * TOT + (w == 0 ? rowA : rowB)] =
                (int)(key & 0xffffffffu);
    }
}

// ------- one smoothing step (edgesT[k][row]: coalesced neighbor loads) -------
__global__ void smooth_kernel(const float* __restrict__ zin,
                              float* __restrict__ zout,
                              const int* __restrict__ edgesT,
                              const int* __restrict__ C) {
    int t = blockIdx.x * blockDim.x + threadIdx.x;
    if (t >= TOT) return;
    float acc = 0.0f;
    if (C[t] > 0) {
        const int b = t >> 13;
        const float* zb = zin + (size_t)b * NN;
#pragma unroll
        for (int k = 0; k < KNB; ++k)
            acc = __fadd_rn(acc, zb[edgesT[(size_t)k * TOT + t]]);
        acc = __fdiv_rn(acc, __fadd_rn(30.0f, 1e-5f));
    }
    zout[t] = acc;
}

// ====== partitioned bitonic argsort: SAME network as the proven single-block
// sort, split into LDS-local stages (j <= 1024, 2048-key chunks) and global
// compare-exchange stages (j >= 2048). Direction up = ((n & k) == 0) uses the
// global row index n everywhere, so the executed compare-exchange set is
// bit-identical to the proven kernel. Keys (monotonic_bits << 32) | n.

// stages k = 2..2048 (all j), fused with key construction from z + prio
__global__ __launch_bounds__(1024) void sort_local_full(
        const float* __restrict__ z, const float* __restrict__ prio,
        unsigned long long* __restrict__ gkeys) {
    __shared__ unsigned long long keys[2048];  // 16 KiB
    const int b = blockIdx.x >> 2;
    const int c = blockIdx.x & 3;              // 2048-chunk within row
    const int base = c * 2048;
    const int t = threadIdx.x;
    for (int i = t; i < 2048; i += 1024) {
        const int n = base + i;
        float v = z[(size_t)b * NN + n] + prio[(size_t)b * NN + n];
        uint32_t u = __float_as_uint(v);
        u ^= (u >> 31) ? 0xFFFFFFFFu : 0x80000000u;  // monotonic float->uint
        keys[i] = ((unsigned long long)u << 32) | (unsigned)n;
    }
    __syncthreads();
    for (int k = 2; k <= 2048; k <<= 1) {
        for (int j = k >> 1; j > 0; j >>= 1) {
            for (int i = t; i < 2048; i += 1024) {
                int ixj = i ^ j;
                if (ixj > i) {
                    unsigned long long a = keys[i], cc = keys[ixj];
                    bool up = (((base + i) & k) == 0);
                    if ((a > cc) == up) { keys[i] = cc; keys[ixj] = a; }
                }
            }
            __syncthreads();
        }
    }
    for (int i = t; i < 2048; i += 1024)
        gkeys[(size_t)b * NN + base + i] = keys[i];
}

// one global stage (j >= 2048): one thread per pair
__global__ void sort_global_step(unsigned long long* __restrict__ gkeys,
                                 int k, int j) {
    int t = blockIdx.x * blockDim.x + threadIdx.x;  // 0 .. TOT/2-1
    const int b = t >> 12;
    const int p = t & 4095;
    const int i = ((p & ~(j - 1)) << 1) | (p & (j - 1));  // i has j-bit clear
    const int ixj = i | j;
    unsigned long long* gk = gkeys + (size_t)b * NN;
    unsigned long long a = gk[i], cc = gk[ixj];
    bool up = ((i & k) == 0);
    if ((a > cc) == up) { gk[i] = cc; gk[ixj] = a; }
}

// finishing stages j = 1024..1 for merge phase k; optionally writes out
__global__ __launch_bounds__(1024) void sort_local_finish(
        unsigned long long* __restrict__ gkeys, int k,
        int* __restrict__ out) {
    __shared__ unsigned long long keys[2048];
    const int b = blockIdx.x >> 2;
    const int c = blockIdx.x & 3;
    const int base = c * 2048;
    const int t = threadIdx.x;
    for (int i = t; i < 2048; i += 1024)
        keys[i] = gkeys[(size_t)b * NN + base + i];
    __syncthreads();
    for (int j = 1024; j > 0; j >>= 1) {
        for (int i = t; i < 2048; i += 1024) {
            int ixj = i ^ j;
            if (ixj > i) {
                unsigned long long a = keys[i], cc = keys[ixj];
                bool up = (((base + i) & k) == 0);
                if ((a > cc) == up) { keys[i] = cc; keys[ixj] = a; }
            }
        }
        __syncthreads();
    }
    if (out != nullptr) {
        for (int i = t; i < 2048; i += 1024)
            out[(size_t)b * NN + base + i] = (int)(keys[i] & 0xffffffffu);
    } else {
        for (int i = t; i < 2048; i += 1024)
            gkeys[(size_t)b * NN + base + i] = keys[i];
    }
}

extern "C" void kernel_launch(void* const* d_in, const int* in_sizes, int n_in,
                              void* d_out, int out_size, void* d_ws, size_t ws_size,
                              hipStream_t stream) {
    const float* X = (const float*)d_in[0];    // [4,8192,3] f32
    const int* C = (const int*)d_in[1];        // [4,8192] int32
    const float* prio = (const float*)d_in[2]; // [4,8192] f32
    int* out = (int*)d_out;                    // [4,8192] i32

    float* z0 = (float*)d_ws;
    float* z1 = z0 + TOT;
    int* edgesT = (int*)(z1 + TOT);            // [KNB][TOT]
    float* Xs = (float*)(edgesT + (size_t)TOT * KNB);  // [NB][3][NN]
    unsigned long long* gkeys =
        (unsigned long long*)(Xs + (size_t)NB * 3 * NN);  // [NB][NN]

    prep_kernel<<<TOT / 256, 256, 0, stream>>>(X, C, z0, Xs);
    knn_kernel<<<TOT / 2, 256, 0, stream>>>(Xs, X, edgesT);

    float* cur = z0;
    float* nxt = z1;
    for (int s = 0; s < 5; ++s) {
        smooth_kernel<<<TOT / 256, 256, 0, stream>>>(cur, nxt, edgesT, C);
        float* tmp = cur; cur = nxt; nxt = tmp;
    }

    // partitioned bitonic argsort (network identical to proven single-block)
    sort_local_full<<<NB * 4, 1024, 0, stream>>>(cur, prio, gkeys);
    sort_global_step<<<TOT / 2 / 256, 256, 0, stream>>>(gkeys, 4096, 2048);
    sort_local_finish<<<NB * 4, 1024, 0, stream>>>(gkeys, 4096, nullptr);
    sort_global_step<<<TOT / 2 / 256, 256, 0, stream>>>(gkeys, 8192, 4096);
    sort_global_step<<<TOT / 2 / 256, 256, 0, stream>>>(gkeys, 8192, 2048);
    sort_local_finish<<<NB * 4, 1024, 0, stream>>>(gkeys, 8192, out);
}